// Round 16
// baseline (184.176 us; speedup 1.0000x reference)
//
#include <hip/hip_runtime.h>
#include <hip/hip_bf16.h>
#include <cstdint>
#include <cstddef>

// Problem constants
constexpr int T_TOK = 4096;   // B*S
constexpr int H_DIM = 1024;
constexpr int E_NUM = 8;
constexpr int I_DIM = 1024;
constexpr int F2    = 2048;   // 2*I
constexpr float ALPHA = 1.702f;
constexpr float LIMIT = 7.0f;
constexpr int BM = 256;       // GEMM row tile
constexpr int BK = 32;        // GEMM k tile
constexpr int NT = 32;        // k-steps (K=1024)
constexpr int MAXT = 40;      // >= sum(ceil(cnt_e/256)) worst case (39)

using u16    = unsigned short;
using bf16x8 = __attribute__((ext_vector_type(8))) __bf16;
using s16x8  = __attribute__((ext_vector_type(8))) short;
using f32x4  = __attribute__((ext_vector_type(4))) float;

// Workspace layout (bytes). GEMM operands BLOCKED+PRE-SWIZZLED (contiguous
// per-(tile-panel,kt) LDS images; staging = wave-contiguous loads).
constexpr size_t WS_W1T  = 0;                        // 33,554,432
constexpr size_t WS_W2T  = 33554432;                 // 16,777,216
constexpr size_t WS_ACT  = 50331648;                 // 20,971,520
constexpr size_t WS_ETOK = 71303168;                 // [E][T] int   131,072
constexpr size_t WS_EW   = 71434240;                 // [E][T] float 131,072
constexpr size_t WS_CNT  = 71565312;                 // [E] int
constexpr size_t WS_ROWB = 71565344;                 // [E] int
constexpr size_t WS_ASGN = 71565376;                 // [MAXT] int (1KB reserved)
constexpr size_t WS_TOPE = 71566400;                 // [T] int
constexpr size_t WS_TOPW = 71582784;                 // [T] float2
constexpr size_t WS_XBF  = 71615552;                 // [T][H] bf16 8,388,608
constexpr size_t WS_NEED = 80004160;

__device__ __forceinline__ u16 f2bf(float f) {
    union { float f; unsigned u; } v; v.f = f;
    return (u16)((v.u + 0x7FFFu + ((v.u >> 16) & 1u)) >> 16);   // RNE
}

__device__ __forceinline__ s16x8 pack8(float4 a, float4 b) {
    s16x8 r;
    r[0] = (short)f2bf(a.x); r[1] = (short)f2bf(a.y);
    r[2] = (short)f2bf(a.z); r[3] = (short)f2bf(a.w);
    r[4] = (short)f2bf(b.x); r[5] = (short)f2bf(b.y);
    r[6] = (short)f2bf(b.z); r[7] = (short)f2bf(b.w);
    return r;
}

// async global -> LDS, 16B per lane. Global source PER-LANE; LDS dest uniform.
__device__ __forceinline__ void gload16(const void* g, void* l) {
    __builtin_amdgcn_global_load_lds((const __attribute__((address_space(1))) unsigned*)g,
                                     (__attribute__((address_space(3))) unsigned*)l,
                                     16, 0, 0);
}

// drain own stage loads + ds ops, then raw barrier (R5/R9/R12/R14-proven).
__device__ __forceinline__ void pipe_sync() {
    __builtin_amdgcn_sched_barrier(0);
    asm volatile("s_waitcnt vmcnt(0) lgkmcnt(0)" ::: "memory");
    __builtin_amdgcn_s_barrier();
    __builtin_amdgcn_sched_barrier(0);
}

// ---------------------------------------------------------------------------
// x fp32 -> bf16 (once)
// ---------------------------------------------------------------------------
__global__ __launch_bounds__(256) void k_xbf(const float* __restrict__ x,
                                             u16* __restrict__ xbf) {
    const size_t i = ((size_t)blockIdx.x * 256 + threadIdx.x) * 8;
    float4 a = *(const float4*)(x + i);
    float4 b = *(const float4*)(x + i + 4);
    *(s16x8*)(xbf + i) = pack8(a, b);
}

// ---------------------------------------------------------------------------
// Transpose gate_up_proj [E][H][2I] fp32 -> blocked+swizzled W1T bf16.
// ---------------------------------------------------------------------------
__global__ __launch_bounds__(256) void k_transpose_w1(const float* __restrict__ in,
                                                      u16* __restrict__ out) {
    __shared__ float tile[64][65];
    const int e = blockIdx.z, c0 = blockIdx.x * 64, h0 = blockIdx.y * 64;
    const int tid = threadIdx.x;
    const float* src = in + ((size_t)e * H_DIM + h0) * F2 + c0;
#pragma unroll
    for (int i = 0; i < 4; ++i) {
        int r = (tid >> 4) + i * 16, c = (tid & 15) * 4;
        float4 v = *(const float4*)(src + (size_t)r * F2 + c);
        tile[r][c] = v.x; tile[r][c + 1] = v.y; tile[r][c + 2] = v.z; tile[r][c + 3] = v.w;
    }
    __syncthreads();
    const int c = tid >> 2, hseg = (tid & 3) * 16;
    const int g = c & 1;
    const int f = (c0 + c) >> 1;                 // act col 0..1023
    s16x8 o0, o1;
#pragma unroll
    for (int j = 0; j < 8; ++j) o0[j] = (short)f2bf(tile[hseg + j][c]);
#pragma unroll
    for (int j = 0; j < 8; ++j) o1[j] = (short)f2bf(tile[hseg + 8 + j][c]);
    const int pan = f >> 6;
    const int brow = g * 64 + (f & 63);
    const int h1 = h0 + hseg;                    // k index of o0
    const int kt = h1 >> 5;
    const int s0 = (h1 & 31) >> 3;               // 0 or 2
    const int xr = (brow >> 1) & 3;
    u16* blk = out + (((size_t)(e * 16 + pan) * 32 + kt) << 12);
    *(s16x8*)(blk + brow * 32 + ((s0 ^ xr) << 3))       = o0;
    *(s16x8*)(blk + brow * 32 + (((s0 + 1) ^ xr) << 3)) = o1;
}

// ---------------------------------------------------------------------------
// Transpose down_proj [E][I][H] fp32 -> blocked+swizzled W2T bf16.
// ---------------------------------------------------------------------------
__global__ __launch_bounds__(256) void k_transpose_w2(const float* __restrict__ in,
                                                      u16* __restrict__ out) {
    __shared__ float tile[64][65];
    const int e = blockIdx.z, h0 = blockIdx.x * 64, i0 = blockIdx.y * 64;
    const int tid = threadIdx.x;
    const float* src = in + ((size_t)e * I_DIM + i0) * H_DIM + h0;
#pragma unroll
    for (int i = 0; i < 4; ++i) {
        int r = (tid >> 4) + i * 16, c = (tid & 15) * 4;
        float4 v = *(const float4*)(src + (size_t)r * H_DIM + c);
        tile[r][c] = v.x; tile[r][c + 1] = v.y; tile[r][c + 2] = v.z; tile[r][c + 3] = v.w;
    }
    __syncthreads();
    const int c = tid >> 2, iseg = (tid & 3) * 16;
    s16x8 o0, o1;
#pragma unroll
    for (int j = 0; j < 8; ++j) o0[j] = (short)f2bf(tile[iseg + j][c]);
#pragma unroll
    for (int j = 0; j < 8; ++j) o1[j] = (short)f2bf(tile[iseg + 8 + j][c]);
    const int hcol = h0 + c;                     // out col 0..1023
    const int pan = hcol >> 7;
    const int brow = hcol & 127;
    const int i1 = i0 + iseg;                    // k index of o0
    const int kt = i1 >> 5;
    const int s0 = (i1 & 31) >> 3;
    const int xr = (brow >> 1) & 3;
    u16* blk = out + (((size_t)(e * 8 + pan) * 32 + kt) << 12);
    *(s16x8*)(blk + brow * 32 + ((s0 ^ xr) << 3))       = o0;
    *(s16x8*)(blk + brow * 32 + (((s0 + 1) ^ xr) << 3)) = o1;
}

// ---------------------------------------------------------------------------
// Router phase 1: fp32 logits, top-2, softmax. One wave per token. No atomics.
// ---------------------------------------------------------------------------
__global__ __launch_bounds__(256) void k_router_top2(const float* __restrict__ x,
                                                     const float* __restrict__ rw,
                                                     int* __restrict__ tope,
                                                     float2* __restrict__ topw) {
    const int wave = threadIdx.x >> 6, lane = threadIdx.x & 63;
    const int t = blockIdx.x * 4 + wave;
    const float* xr = x + (size_t)t * H_DIM;
    float acc[E_NUM];
#pragma unroll
    for (int e = 0; e < E_NUM; ++e) acc[e] = 0.f;
    for (int h = lane; h < H_DIM; h += 64) {
        float xv = xr[h];
        const float* r = rw + h * E_NUM;
#pragma unroll
        for (int e = 0; e < E_NUM; ++e) acc[e] += xv * r[e];
    }
#pragma unroll
    for (int e = 0; e < E_NUM; ++e) {
        float v = acc[e];
#pragma unroll
        for (int o = 32; o > 0; o >>= 1) v += __shfl_down(v, o);
        acc[e] = v;
    }
    if (lane == 0) {
        int e0 = 0; float v0 = acc[0];
#pragma unroll
        for (int e = 1; e < E_NUM; ++e) if (acc[e] > v0) { v0 = acc[e]; e0 = e; }
        int e1 = -1; float v1 = -3.4e38f;
#pragma unroll
        for (int e = 0; e < E_NUM; ++e) if (e != e0 && acc[e] > v1) { v1 = acc[e]; e1 = e; }
        float ew = expf(v1 - v0);
        float inv = 1.f / (1.f + ew);
        tope[t] = e0 | (e1 << 8);
        topw[t] = make_float2(inv, ew * inv);
    }
}

// ---------------------------------------------------------------------------
// Router phase 2: block-aggregated scatter (1 global atomic per expert/block).
// Writes per-entry token AND routing weight (gemm2 fuses the combine).
// ---------------------------------------------------------------------------
__global__ __launch_bounds__(256) void k_router_scatter(const int* __restrict__ tope,
                                                        const float2* __restrict__ topw,
                                                        int* __restrict__ cnt,
                                                        int* __restrict__ ent_tok,
                                                        float* __restrict__ ent_w) {
    __shared__ int lcnt[E_NUM];
    __shared__ int gbase[E_NUM];
    const int tid = threadIdx.x;
    const int t = blockIdx.x * 256 + tid;
    if (tid < E_NUM) lcnt[tid] = 0;
    __syncthreads();
    const int pk = tope[t];
    const float2 w = topw[t];
    const int e0 = pk & 0xff, e1 = pk >> 8;
    const int o0 = atomicAdd(&lcnt[e0], 1);
    const int o1 = atomicAdd(&lcnt[e1], 1);
    __syncthreads();
    if (tid < E_NUM) gbase[tid] = atomicAdd(&cnt[tid], lcnt[tid]);
    __syncthreads();
    const int p0 = gbase[e0] + o0;
    const int p1 = gbase[e1] + o1;
    ent_tok[e0 * T_TOK + p0] = t; ent_w[e0 * T_TOK + p0] = w.x;
    ent_tok[e1 * T_TOK + p1] = t; ent_w[e1 * T_TOK + p1] = w.y;
}

// ---------------------------------------------------------------------------
// Schedule: parallel global I/O, serial (register/LDS-only) prefix on lane 0.
// 256-ALIGNED row bases + tile assignment table (BM=256).
// ---------------------------------------------------------------------------
__global__ void k_schedule(const int* __restrict__ cnt, int* __restrict__ rowbase,
                           int* __restrict__ assign) {
    __shared__ int sc[E_NUM], srb[E_NUM], sasg[MAXT];
    const int tid = threadIdx.x;
    if (tid < E_NUM) sc[tid] = cnt[tid];
    __syncthreads();
    if (tid == 0) {
        int rb = 0, na = 0;
        for (int e = 0; e < E_NUM; ++e) {
            srb[e] = rb;
            const int nt = (sc[e] + 255) >> 8;
            for (int m = 0; m < nt; ++m) sasg[na++] = (e << 16) | m;
            rb += sc[e];
            rb = (rb + 255) & ~255;          // align next expert's base
        }
        for (; na < MAXT; ++na) sasg[na] = -1;
    }
    __syncthreads();
    if (tid < E_NUM) rowbase[tid] = srb[tid];
    if (tid < MAXT) assign[tid] = sasg[tid];
}

// ---------------------------------------------------------------------------
// GEMM1: 256 entries x 64 act-cols ([gate64|up64] B-rows), BK=32, 512 thr /
// 8 waves (4Mx2N). Double-buffered 48KB LDS (R14 exact body). A from XBF
// (per-lane inverse-swizzled); B contiguous from blocked W1T (+lane*8).
// Epilogue writes blocked+swizzled ACT.
// ---------------------------------------------------------------------------
__global__ __launch_bounds__(512, 4) void k_gemm1(
    const u16* __restrict__ xbf, const u16* __restrict__ w1t,
    const float* __restrict__ bias, const int* __restrict__ ent_tok,
    const int* __restrict__ cnt, const int* __restrict__ rowbase,
    const int* __restrict__ assign, u16* __restrict__ act) {
    const int a = assign[blockIdx.y];
    if (a < 0) return;
    const int e = a >> 16, mt = a & 0xffff;
    const int pan = blockIdx.x;               // 16 panels of 64 act-cols
    const int j0 = pan * 64;
    const int cs = cnt[e], r0 = mt * BM;
    __shared__ __align__(16) u16 As[2][BM * BK];    // 2 x 16KB
    __shared__ __align__(16) u16 Bs[2][128 * BK];   // 2 x 8KB
    const int tid = threadIdx.x, lane = tid & 63, wv = tid >> 6;
    const int lr = lane >> 2;                       // row-in-16 (0..15)
    const int sm = (lane & 3) ^ ((lr >> 1) & 3);    // inverse-swizzled src slot
    const u16* asrc[2]; int dofsA[2];
#pragma unroll
    for (int j = 0; j < 2; ++j) {
        const int row = wv * 32 + j * 16 + lr;      // 0..255
        const int aent = r0 + row;
        const int tok = (aent < cs) ? ent_tok[e * T_TOK + aent] : 0;
        asrc[j] = xbf + (size_t)tok * H_DIM + sm * 8;
        dofsA[j] = (wv * 32 + j * 16) * BK;
    }
    const u16* bblk = w1t + ((size_t)(e * 16 + pan) * 32) * 4096 + wv * 512 + lane * 8;
    const int dofsB = wv * 512;
    const int wm = wv >> 1, wn = wv & 1;            // 4M x 2N
    const int lcol = lane & 15, lk = lane >> 4;
    int aoff[4], goff[2], uoff[2];
#pragma unroll
    for (int mi = 0; mi < 4; ++mi) {
        const int r = wm * 64 + mi * 16 + lcol;
        aoff[mi] = r * 64 + ((lk ^ ((r >> 1) & 3)) << 4);
    }
#pragma unroll
    for (int nj = 0; nj < 2; ++nj) {
        const int rg_ = wn * 32 + nj * 16 + lcol;
        const int ru  = 64 + rg_;
        goff[nj] = rg_ * 64 + ((lk ^ ((rg_ >> 1) & 3)) << 4);
        uoff[nj] = ru  * 64 + ((lk ^ ((ru  >> 1) & 3)) << 4);
    }
    f32x4 ag[4][2], au[4][2];
    const f32x4 z = {0.f, 0.f, 0.f, 0.f};
#pragma unroll
    for (int mi = 0; mi < 4; ++mi) { ag[mi][0] = z; ag[mi][1] = z; au[mi][0] = z; au[mi][1] = z; }
#pragma unroll
    for (int j = 0; j < 2; ++j) gload16(asrc[j], &As[0][dofsA[j]]);
    gload16(bblk, &Bs[0][dofsB]);
    pipe_sync();
    int cur = 0;
    for (int t = 0; t < NT; ++t) {
        if (t + 1 < NT) {                      // issue next-tile stage FIRST
            const int kn = (t + 1) * BK;
            u16* Ad = As[cur ^ 1]; u16* Bd = Bs[cur ^ 1];
#pragma unroll
            for (int j = 0; j < 2; ++j) gload16(asrc[j] + kn, Ad + dofsA[j]);
            gload16(bblk + (size_t)(t + 1) * 4096, Bd + dofsB);
        }
        const char* Ab = (const char*)As[cur];
        const char* Bb = (const char*)Bs[cur];
        bf16x8 af[4];
#pragma unroll
        for (int mi = 0; mi < 4; ++mi) af[mi] = *(const bf16x8*)(Ab + aoff[mi]);
        const bf16x8 g0 = *(const bf16x8*)(Bb + goff[0]);
        const bf16x8 g1 = *(const bf16x8*)(Bb + goff[1]);
        const bf16x8 u0 = *(const bf16x8*)(Bb + uoff[0]);
        const bf16x8 u1 = *(const bf16x8*)(Bb + uoff[1]);
#pragma unroll
        for (int mi = 0; mi < 4; ++mi) {
            ag[mi][0] = __builtin_amdgcn_mfma_f32_16x16x32_bf16(af[mi], g0, ag[mi][0], 0, 0, 0);
            au[mi][0] = __builtin_amdgcn_mfma_f32_16x16x32_bf16(af[mi], u0, au[mi][0], 0, 0, 0);
            ag[mi][1] = __builtin_amdgcn_mfma_f32_16x16x32_bf16(af[mi], g1, ag[mi][1], 0, 0, 0);
            au[mi][1] = __builtin_amdgcn_mfma_f32_16x16x32_bf16(af[mi], u1, au[mi][1], 0, 0, 0);
        }
        pipe_sync();                           // next-tile stage drained (hidden under compute)
        cur ^= 1;
    }
    // epilogue: clamp + GLU, store bf16 act into BLOCKED+SWIZZLED layout
    const int rbase = rowbase[e];
#pragma unroll
    for (int mi = 0; mi < 4; ++mi) {
#pragma unroll
        for (int nj = 0; nj < 2; ++nj) {
            const int col = j0 + wn * 32 + nj * 16 + lcol;
            const float bg_ = bias[e * F2 + 2 * col];
            const float bu_ = bias[e * F2 + 2 * col + 1];
            const int kt = col >> 5, slot = (col & 31) >> 3, ke = col & 7;
#pragma unroll
            for (int rg = 0; rg < 4; ++rg) {
                const int r = wm * 64 + mi * 16 + lk * 4 + rg;
                if (r0 + r < cs) {
                    float gv = ag[mi][nj][rg] + bg_;
                    float uv = au[mi][nj][rg] + bu_;
                    gv = fminf(gv, LIMIT);
                    uv = fminf(fmaxf(uv, -LIMIT), LIMIT);
                    const float glu = gv / (1.f + expf(-ALPHA * gv));
                    const int grow = rbase + r0 + r;
                    const int rr = grow & 255;
                    act[((size_t)(grow >> 8) * 32 + kt) * 8192 + rr * 32 +
                        ((slot ^ ((rr >> 1) & 3)) << 3) + ke] = f2bf((uv + 1.f) * glu);
                }
            }
        }
    }
}

// ---------------------------------------------------------------------------
// GEMM2 (+fused combine): 256 entries x 128 out-cols, BK=32, R14 pipeline.
// Epilogue: out[tok] += w_ent * (acc + b2) via fp32 atomicAdd (out pre-zeroed).
// ---------------------------------------------------------------------------
__global__ __launch_bounds__(512, 4) void k_gemm2(
    const u16* __restrict__ actb, const u16* __restrict__ w2t,
    const float* __restrict__ b2, const int* __restrict__ ent_tok,
    const float* __restrict__ ent_w, const int* __restrict__ cnt,
    const int* __restrict__ rowbase, const int* __restrict__ assign,
    float* __restrict__ out) {
    const int a = assign[blockIdx.y];
    if (a < 0) return;
    const int e = a >> 16, mt = a & 0xffff;
    const int pan = blockIdx.x;               // 8 panels of 128 out-cols
    const int n0 = pan * 128;
    const int cs = cnt[e], r0 = mt * BM, rbase = rowbase[e];
    __shared__ __align__(16) u16 As[2][BM * BK];    // 2 x 16KB
    __shared__ __align__(16) u16 Bs[2][128 * BK];   // 2 x 8KB
    const int tid = threadIdx.x, lane = tid & 63, wv = tid >> 6;
    const u16* ablk = actb + ((size_t)((rbase + r0) >> 8) * 32) * 8192 + wv * 1024 + lane * 8;
    const u16* bblk = w2t + ((size_t)(e * 8 + pan) * 32) * 4096 + wv * 512 + lane * 8;
    const int dofsB = wv * 512;
    const int wm = wv >> 1, wn = wv & 1;
    const int lcol = lane & 15, lk = lane >> 4;
    int aoff[4], boff[4];
#pragma unroll
    for (int mi = 0; mi < 4; ++mi) {
        const int r = wm * 64 + mi * 16 + lcol;
        aoff[mi] = r * 64 + ((lk ^ ((r >> 1) & 3)) << 4);
    }
#pragma unroll
    for (int nj = 0; nj < 4; ++nj) {
        const int b = wn * 64 + nj * 16 + lcol;     // 0..127
        boff[nj] = b * 64 + ((lk ^ ((b >> 1) & 3)) << 4);
    }
    f32x4 acc[4][4];
    const f32x4 z = {0.f, 0.f, 0.f, 0.f};
#pragma unroll
    for (int mi = 0; mi < 4; ++mi)
#pragma unroll
        for (int nj = 0; nj < 4; ++nj) acc[mi][nj] = z;
#pragma unroll
    for (int j = 0; j < 2; ++j) gload16(ablk + j * 512, &As[0][wv * 1024 + j * 512]);
    gload16(bblk, &Bs[0][dofsB]);
    pipe_sync();
    int cur = 0;
    for (int t = 0; t < NT; ++t) {
        if (t + 1 < NT) {
            u16* Ad = As[cur ^ 1]; u16* Bd = Bs[cur ^ 1];
#pragma unroll
            for (int j = 0; j < 2; ++j)
                gload16(ablk + (size_t)(t + 1) * 8192 + j * 512, Ad + wv * 1024 + j * 512);
            gload16(bblk + (size_t)(t + 1) * 4096, Bd + dofsB);
        }
        const char* Ab = (const char*)As[cur];
        const char* Bb = (const char*)Bs[cur];
        bf16x8 af[4], bf_[4];
#pragma unroll
        for (int mi = 0; mi < 4; ++mi) af[mi]  = *(const bf16x8*)(Ab + aoff[mi]);
#pragma unroll
        for (int nj = 0; nj < 4; ++nj) bf_[nj] = *(const bf16x8*)(Bb + boff[nj]);
#pragma unroll
        for (int mi = 0; mi < 4; ++mi)
#pragma unroll
            for (int nj = 0; nj < 4; ++nj)
                acc[mi][nj] = __builtin_amdgcn_mfma_f32_16x16x32_bf16(af[mi], bf_[nj], acc[mi][nj], 0, 0, 0);
        pipe_sync();
        cur ^= 1;
    }
    // fused combine epilogue: out[tok] += w * (acc + b2)
#pragma unroll
    for (int mi = 0; mi < 4; ++mi) {
#pragma unroll
        for (int rg = 0; rg < 4; ++rg) {
            const int r = wm * 64 + mi * 16 + lk * 4 + rg;
            const int ent = r0 + r;
            if (ent < cs) {
                const int tok = ent_tok[e * T_TOK + ent];
                const float w = ent_w[e * T_TOK + ent];
#pragma unroll
                for (int nj = 0; nj < 4; ++nj) {
                    const int col = n0 + wn * 64 + nj * 16 + lcol;
                    atomicAdd(&out[(size_t)tok * H_DIM + col],
                              w * (acc[mi][nj][rg] + b2[e * H_DIM + col]));
                }
            }
        }
    }
}

// ---------------------------------------------------------------------------
extern "C" void kernel_launch(void* const* d_in, const int* in_sizes, int n_in,
                              void* d_out, int out_size, void* d_ws, size_t ws_size,
                              hipStream_t stream) {
    const float* x   = (const float*)d_in[0];
    const float* rw  = (const float*)d_in[1];
    const float* w1  = (const float*)d_in[2];
    const float* b1  = (const float*)d_in[3];
    const float* w2  = (const float*)d_in[4];
    const float* b2  = (const float*)d_in[5];
    float* out = (float*)d_out;
    char* ws = (char*)d_ws;

    if (ws_size < WS_NEED) return;

    u16*    W1T  = (u16*)(ws + WS_W1T);
    u16*    W2T  = (u16*)(ws + WS_W2T);
    u16*    ACT  = (u16*)(ws + WS_ACT);
    int*    ETOK = (int*)(ws + WS_ETOK);
    float*  EW   = (float*)(ws + WS_EW);
    int*    CNT  = (int*)(ws + WS_CNT);
    int*    ROWB = (int*)(ws + WS_ROWB);
    int*    ASGN = (int*)(ws + WS_ASGN);
    int*    TOPE = (int*)(ws + WS_TOPE);
    float2* TOPW = (float2*)(ws + WS_TOPW);
    u16*    XBF  = (u16*)(ws + WS_XBF);

    hipMemsetAsync(CNT, 0, E_NUM * sizeof(int), stream);
    hipMemsetAsync(out, 0, (size_t)T_TOK * H_DIM * sizeof(float), stream);

    k_xbf<<<T_TOK * H_DIM / 2048, 256, 0, stream>>>(x, XBF);
    k_transpose_w1<<<dim3(32, 16, 8), 256, 0, stream>>>(w1, W1T);
    k_transpose_w2<<<dim3(16, 16, 8), 256, 0, stream>>>(w2, W2T);
    k_router_top2<<<T_TOK / 4, 256, 0, stream>>>(x, rw, TOPE, TOPW);
    k_router_scatter<<<T_TOK / 256, 256, 0, stream>>>(TOPE, TOPW, CNT, ETOK, EW);
    k_schedule<<<1, 64, 0, stream>>>(CNT, ROWB, ASGN);
    k_gemm1<<<dim3(16, MAXT), 512, 0, stream>>>(XBF, W1T, b1, ETOK, CNT, ROWB, ASGN, ACT);
    k_gemm2<<<dim3(8, MAXT), 512, 0, stream>>>(ACT, W2T, b2, ETOK, EW, CNT, ROWB, ASGN, out);
}

// Round 17
// 163.370 us; speedup vs baseline: 1.1274x; 1.1274x over previous
//
#include <hip/hip_runtime.h>
#include <hip/hip_bf16.h>
#include <cstdint>
#include <cstddef>

// Problem constants
constexpr int T_TOK = 4096;   // B*S
constexpr int H_DIM = 1024;
constexpr int E_NUM = 8;
constexpr int I_DIM = 1024;
constexpr int F2    = 2048;   // 2*I
constexpr float ALPHA = 1.702f;
constexpr float LIMIT = 7.0f;
constexpr int BM = 256;       // GEMM row tile
constexpr int BK = 32;        // GEMM k tile
constexpr int NT = 32;        // k-steps (K=1024)
constexpr int MAXT = 40;      // >= sum(ceil(cnt_e/256)) worst case (39)

using u16    = unsigned short;
using bf16x8 = __attribute__((ext_vector_type(8))) __bf16;
using s16x8  = __attribute__((ext_vector_type(8))) short;
using f32x4  = __attribute__((ext_vector_type(4))) float;

// Workspace layout (bytes). All GEMM operands stored BLOCKED+PRE-SWIZZLED:
// block(matrix, tile-panel, kt) is a contiguous image of the LDS tile.
// W1T blk: [e][pan16][kt32] of 128rows x 32k  (8KB blocks)  = 32MB
// W2T blk: [e][pan8][kt32]  of 128rows x 32k  (8KB blocks)  = 16MB
// ACT blk: [rowblk40][kt32] of 256rows x 32k  (16KB blocks) = 20MB (padded rows)
// DOWN aliases W1T (gemm1 done with W1T before gemm2 writes DOWN).
constexpr size_t WS_W1T  = 0;                        // 33,554,432
constexpr size_t WS_DOWN = 0;                        // [10232][1024] bf16 alias
constexpr size_t WS_W2T  = 33554432;                 // 16,777,216
constexpr size_t WS_ACT  = 50331648;                 // 20,971,520
constexpr size_t WS_ETOK = 71303168;                 // [E][T] int
constexpr size_t WS_POS  = 71434240;                 // [T] int2
constexpr size_t WS_CNT  = 71467008;                 // [E] int
constexpr size_t WS_ROWB = 71467040;                 // [E] int
constexpr size_t WS_ASGN = 71467072;                 // [MAXT] int (1KB reserved)
constexpr size_t WS_TOPE = 71468096;                 // [T] int
constexpr size_t WS_TOPW = 71484480;                 // [T] float2
constexpr size_t WS_XBF  = 71517248;                 // [T][H] bf16
constexpr size_t WS_NEED = 79905856;

__device__ __forceinline__ u16 f2bf(float f) {
    union { float f; unsigned u; } v; v.f = f;
    return (u16)((v.u + 0x7FFFu + ((v.u >> 16) & 1u)) >> 16);   // RNE
}
__device__ __forceinline__ float bf2f(u16 u) {
    union { unsigned u; float f; } v; v.u = (unsigned)u << 16; return v.f;
}

__device__ __forceinline__ s16x8 pack8(float4 a, float4 b) {
    s16x8 r;
    r[0] = (short)f2bf(a.x); r[1] = (short)f2bf(a.y);
    r[2] = (short)f2bf(a.z); r[3] = (short)f2bf(a.w);
    r[4] = (short)f2bf(b.x); r[5] = (short)f2bf(b.y);
    r[6] = (short)f2bf(b.z); r[7] = (short)f2bf(b.w);
    return r;
}

// async global -> LDS, 16B per lane. GLOBAL SOURCE IS PER-LANE; LDS dest is
// wave-uniform base + lane*16.
__device__ __forceinline__ void gload16(const void* g, void* l) {
    __builtin_amdgcn_global_load_lds((const __attribute__((address_space(1))) unsigned*)g,
                                     (__attribute__((address_space(3))) unsigned*)l,
                                     16, 0, 0);
}

// drain own stage loads + ds ops, then raw barrier (R5/R9/R12-proven).
__device__ __forceinline__ void pipe_sync() {
    __builtin_amdgcn_sched_barrier(0);
    asm volatile("s_waitcnt vmcnt(0) lgkmcnt(0)" ::: "memory");
    __builtin_amdgcn_s_barrier();
    __builtin_amdgcn_sched_barrier(0);
}

// ---------------------------------------------------------------------------
// x fp32 -> bf16 (once)
// ---------------------------------------------------------------------------
__global__ __launch_bounds__(256) void k_xbf(const float* __restrict__ x,
                                             u16* __restrict__ xbf) {
    const size_t i = ((size_t)blockIdx.x * 256 + threadIdx.x) * 8;
    float4 a = *(const float4*)(x + i);
    float4 b = *(const float4*)(x + i + 4);
    *(s16x8*)(xbf + i) = pack8(a, b);
}

// ---------------------------------------------------------------------------
// Transpose gate_up_proj [E][H][2I] fp32 -> blocked+swizzled W1T bf16:
// block(e,pan,kt): rows [gate64|up64] of panel's 64 act-cols, 32 k (8KB).
// ---------------------------------------------------------------------------
__global__ __launch_bounds__(256) void k_transpose_w1(const float* __restrict__ in,
                                                      u16* __restrict__ out) {
    __shared__ float tile[64][65];
    const int e = blockIdx.z, c0 = blockIdx.x * 64, h0 = blockIdx.y * 64;
    const int tid = threadIdx.x;
    const float* src = in + ((size_t)e * H_DIM + h0) * F2 + c0;
#pragma unroll
    for (int i = 0; i < 4; ++i) {
        int r = (tid >> 4) + i * 16, c = (tid & 15) * 4;
        float4 v = *(const float4*)(src + (size_t)r * F2 + c);
        tile[r][c] = v.x; tile[r][c + 1] = v.y; tile[r][c + 2] = v.z; tile[r][c + 3] = v.w;
    }
    __syncthreads();
    const int c = tid >> 2, hseg = (tid & 3) * 16;
    const int g = c & 1;
    const int f = (c0 + c) >> 1;                 // act col 0..1023
    s16x8 o0, o1;
#pragma unroll
    for (int j = 0; j < 8; ++j) o0[j] = (short)f2bf(tile[hseg + j][c]);
#pragma unroll
    for (int j = 0; j < 8; ++j) o1[j] = (short)f2bf(tile[hseg + 8 + j][c]);
    const int pan = f >> 6;
    const int brow = g * 64 + (f & 63);
    const int h1 = h0 + hseg;                    // k index of o0
    const int kt = h1 >> 5;
    const int s0 = (h1 & 31) >> 3;               // 0 or 2
    const int xr = (brow >> 1) & 3;
    u16* blk = out + (((size_t)(e * 16 + pan) * 32 + kt) << 12);
    *(s16x8*)(blk + brow * 32 + ((s0 ^ xr) << 3))       = o0;
    *(s16x8*)(blk + brow * 32 + (((s0 + 1) ^ xr) << 3)) = o1;
}

// ---------------------------------------------------------------------------
// Transpose down_proj [E][I][H] fp32 -> blocked+swizzled W2T bf16:
// block(e,pan,kt): 128 out-col rows x 32 k (8KB), same swizzle.
// ---------------------------------------------------------------------------
__global__ __launch_bounds__(256) void k_transpose_w2(const float* __restrict__ in,
                                                      u16* __restrict__ out) {
    __shared__ float tile[64][65];
    const int e = blockIdx.z, h0 = blockIdx.x * 64, i0 = blockIdx.y * 64;
    const int tid = threadIdx.x;
    const float* src = in + ((size_t)e * I_DIM + i0) * H_DIM + h0;
#pragma unroll
    for (int i = 0; i < 4; ++i) {
        int r = (tid >> 4) + i * 16, c = (tid & 15) * 4;
        float4 v = *(const float4*)(src + (size_t)r * H_DIM + c);
        tile[r][c] = v.x; tile[r][c + 1] = v.y; tile[r][c + 2] = v.z; tile[r][c + 3] = v.w;
    }
    __syncthreads();
    const int c = tid >> 2, iseg = (tid & 3) * 16;
    s16x8 o0, o1;
#pragma unroll
    for (int j = 0; j < 8; ++j) o0[j] = (short)f2bf(tile[iseg + j][c]);
#pragma unroll
    for (int j = 0; j < 8; ++j) o1[j] = (short)f2bf(tile[iseg + 8 + j][c]);
    const int hcol = h0 + c;                     // out col 0..1023
    const int pan = hcol >> 7;
    const int brow = hcol & 127;
    const int i1 = i0 + iseg;                    // k index of o0
    const int kt = i1 >> 5;
    const int s0 = (i1 & 31) >> 3;
    const int xr = (brow >> 1) & 3;
    u16* blk = out + (((size_t)(e * 8 + pan) * 32 + kt) << 12);
    *(s16x8*)(blk + brow * 32 + ((s0 ^ xr) << 3))       = o0;
    *(s16x8*)(blk + brow * 32 + (((s0 + 1) ^ xr) << 3)) = o1;
}

// ---------------------------------------------------------------------------
// Router phase 1: fp32 logits, top-2, softmax. One wave per token. No atomics.
// ---------------------------------------------------------------------------
__global__ __launch_bounds__(256) void k_router_top2(const float* __restrict__ x,
                                                     const float* __restrict__ rw,
                                                     int* __restrict__ tope,
                                                     float2* __restrict__ topw) {
    const int wave = threadIdx.x >> 6, lane = threadIdx.x & 63;
    const int t = blockIdx.x * 4 + wave;
    const float* xr = x + (size_t)t * H_DIM;
    float acc[E_NUM];
#pragma unroll
    for (int e = 0; e < E_NUM; ++e) acc[e] = 0.f;
    for (int h = lane; h < H_DIM; h += 64) {
        float xv = xr[h];
        const float* r = rw + h * E_NUM;
#pragma unroll
        for (int e = 0; e < E_NUM; ++e) acc[e] += xv * r[e];
    }
#pragma unroll
    for (int e = 0; e < E_NUM; ++e) {
        float v = acc[e];
#pragma unroll
        for (int o = 32; o > 0; o >>= 1) v += __shfl_down(v, o);
        acc[e] = v;
    }
    if (lane == 0) {
        int e0 = 0; float v0 = acc[0];
#pragma unroll
        for (int e = 1; e < E_NUM; ++e) if (acc[e] > v0) { v0 = acc[e]; e0 = e; }
        int e1 = -1; float v1 = -3.4e38f;
#pragma unroll
        for (int e = 0; e < E_NUM; ++e) if (e != e0 && acc[e] > v1) { v1 = acc[e]; e1 = e; }
        float ew = expf(v1 - v0);
        float inv = 1.f / (1.f + ew);
        tope[t] = e0 | (e1 << 8);
        topw[t] = make_float2(inv, ew * inv);
    }
}

// ---------------------------------------------------------------------------
// Router phase 2: block-aggregated scatter (1 global atomic per expert/block).
// ---------------------------------------------------------------------------
__global__ __launch_bounds__(256) void k_router_scatter(const int* __restrict__ tope,
                                                        int* __restrict__ cnt,
                                                        int* __restrict__ ent_tok,
                                                        int2* __restrict__ pos) {
    __shared__ int lcnt[E_NUM];
    __shared__ int gbase[E_NUM];
    const int tid = threadIdx.x;
    const int t = blockIdx.x * 256 + tid;
    if (tid < E_NUM) lcnt[tid] = 0;
    __syncthreads();
    const int pk = tope[t];
    const int e0 = pk & 0xff, e1 = pk >> 8;
    const int o0 = atomicAdd(&lcnt[e0], 1);
    const int o1 = atomicAdd(&lcnt[e1], 1);
    __syncthreads();
    if (tid < E_NUM) gbase[tid] = atomicAdd(&cnt[tid], lcnt[tid]);
    __syncthreads();
    const int p0 = gbase[e0] + o0;
    const int p1 = gbase[e1] + o1;
    ent_tok[e0 * T_TOK + p0] = t;
    ent_tok[e1 * T_TOK + p1] = t;
    pos[t] = make_int2(p0, p1);
}

// ---------------------------------------------------------------------------
// Schedule: 256-ALIGNED row bases (so ACT row-blocks align with gemm2 tiles)
// + tile assignment table (BM=256 tiles, shared by both GEMMs).
// ---------------------------------------------------------------------------
__global__ void k_schedule(const int* __restrict__ cnt, int* __restrict__ rowbase,
                           int* __restrict__ assign) {
    if (threadIdx.x == 0) {
        int rb = 0, na = 0;
        for (int e = 0; e < E_NUM; ++e) {
            rowbase[e] = rb;
            int nt = (cnt[e] + BM - 1) >> 8;
            for (int m = 0; m < nt; ++m) assign[na++] = (e << 16) | m;
            rb += cnt[e];
            rb = (rb + 255) & ~255;          // align next expert's base
        }
        for (; na < MAXT; ++na) assign[na] = -1;
    }
}

// ---------------------------------------------------------------------------
// GEMM1: 256 entries x 64 act-cols ([gate64|up64] B-rows), BK=32, 512 thr /
// 8 waves (4Mx2N). Double-buffered 48KB LDS -> 2 blocks/CU (16 waves/CU).
// A staged from XBF (token rows) with inverse swizzle; B staged CONTIGUOUS
// from blocked W1T (per-lane source = blk + lane*8).
// Epilogue writes blocked+swizzled ACT for gemm2's contiguous A staging.
// ---------------------------------------------------------------------------
__global__ __launch_bounds__(512, 4) void k_gemm1(
    const u16* __restrict__ xbf, const u16* __restrict__ w1t,
    const float* __restrict__ bias, const int* __restrict__ ent_tok,
    const int* __restrict__ cnt, const int* __restrict__ rowbase,
    const int* __restrict__ assign, u16* __restrict__ act) {
    const int a = assign[blockIdx.y];
    if (a < 0) return;
    const int e = a >> 16, mt = a & 0xffff;
    const int pan = blockIdx.x;               // 16 panels of 64 act-cols
    const int j0 = pan * 64;
    const int cs = cnt[e], r0 = mt * BM;
    __shared__ __align__(16) u16 As[2][BM * BK];    // 2 x 16KB
    __shared__ __align__(16) u16 Bs[2][128 * BK];   // 2 x 8KB
    const int tid = threadIdx.x, lane = tid & 63, wv = tid >> 6;
    const int lr = lane >> 2;                       // row-in-16 (0..15)
    const int sm = (lane & 3) ^ ((lr >> 1) & 3);    // inverse-swizzled src slot
    // A staging: 2 instrs/thread over XBF token rows (per-lane source)
    const u16* asrc[2]; int dofsA[2];
#pragma unroll
    for (int j = 0; j < 2; ++j) {
        const int row = wv * 32 + j * 16 + lr;      // 0..255
        const int aent = r0 + row;
        const int tok = (aent < cs) ? ent_tok[e * T_TOK + aent] : 0;
        asrc[j] = xbf + (size_t)tok * H_DIM + sm * 8;
        dofsA[j] = (wv * 32 + j * 16) * BK;
    }
    // B staging: contiguous 1KB/wave from blocked W1T; PER-LANE src +lane*8
    const u16* bblk = w1t + ((size_t)(e * 16 + pan) * 32) * 4096 + wv * 512 + lane * 8;
    const int dofsB = wv * 512;                     // wave-uniform LDS base
    // compute-side byte offsets (loop-invariant)
    const int wm = wv >> 1, wn = wv & 1;            // 4M x 2N
    const int lcol = lane & 15, lk = lane >> 4;
    int aoff[4], goff[2], uoff[2];
#pragma unroll
    for (int mi = 0; mi < 4; ++mi) {
        const int r = wm * 64 + mi * 16 + lcol;
        aoff[mi] = r * 64 + ((lk ^ ((r >> 1) & 3)) << 4);
    }
#pragma unroll
    for (int nj = 0; nj < 2; ++nj) {
        const int rg_ = wn * 32 + nj * 16 + lcol;
        const int ru  = 64 + rg_;
        goff[nj] = rg_ * 64 + ((lk ^ ((rg_ >> 1) & 3)) << 4);
        uoff[nj] = ru  * 64 + ((lk ^ ((ru  >> 1) & 3)) << 4);
    }
    f32x4 ag[4][2], au[4][2];
    const f32x4 z = {0.f, 0.f, 0.f, 0.f};
#pragma unroll
    for (int mi = 0; mi < 4; ++mi) { ag[mi][0] = z; ag[mi][1] = z; au[mi][0] = z; au[mi][1] = z; }
    // prologue: stage k-tile 0
#pragma unroll
    for (int j = 0; j < 2; ++j) gload16(asrc[j], &As[0][dofsA[j]]);
    gload16(bblk, &Bs[0][dofsB]);
    pipe_sync();
    int cur = 0;
    for (int t = 0; t < NT; ++t) {
        if (t + 1 < NT) {                      // issue next-tile stage FIRST
            const int kn = (t + 1) * BK;
            u16* Ad = As[cur ^ 1]; u16* Bd = Bs[cur ^ 1];
#pragma unroll
            for (int j = 0; j < 2; ++j) gload16(asrc[j] + kn, Ad + dofsA[j]);
            gload16(bblk + (t + 1) * 4096, Bd + dofsB);
        }
        const char* Ab = (const char*)As[cur];
        const char* Bb = (const char*)Bs[cur];
        bf16x8 af[4];
#pragma unroll
        for (int mi = 0; mi < 4; ++mi) af[mi] = *(const bf16x8*)(Ab + aoff[mi]);
        const bf16x8 g0 = *(const bf16x8*)(Bb + goff[0]);
        const bf16x8 g1 = *(const bf16x8*)(Bb + goff[1]);
        const bf16x8 u0 = *(const bf16x8*)(Bb + uoff[0]);
        const bf16x8 u1 = *(const bf16x8*)(Bb + uoff[1]);
#pragma unroll
        for (int mi = 0; mi < 4; ++mi) {
            ag[mi][0] = __builtin_amdgcn_mfma_f32_16x16x32_bf16(af[mi], g0, ag[mi][0], 0, 0, 0);
            au[mi][0] = __builtin_amdgcn_mfma_f32_16x16x32_bf16(af[mi], u0, au[mi][0], 0, 0, 0);
            ag[mi][1] = __builtin_amdgcn_mfma_f32_16x16x32_bf16(af[mi], g1, ag[mi][1], 0, 0, 0);
            au[mi][1] = __builtin_amdgcn_mfma_f32_16x16x32_bf16(af[mi], u1, au[mi][1], 0, 0, 0);
        }
        pipe_sync();                           // next-tile stage drained (hidden under compute)
        cur ^= 1;
    }
    // epilogue: clamp + GLU, store bf16 act into BLOCKED+SWIZZLED layout
    const int rbase = rowbase[e];
#pragma unroll
    for (int mi = 0; mi < 4; ++mi) {
#pragma unroll
        for (int nj = 0; nj < 2; ++nj) {
            const int col = j0 + wn * 32 + nj * 16 + lcol;
            const float bg_ = bias[e * F2 + 2 * col];
            const float bu_ = bias[e * F2 + 2 * col + 1];
            const int kt = col >> 5, slot = (col & 31) >> 3, ke = col & 7;
#pragma unroll
            for (int rg = 0; rg < 4; ++rg) {
                const int r = wm * 64 + mi * 16 + lk * 4 + rg;
                if (r0 + r < cs) {
                    float gv = ag[mi][nj][rg] + bg_;
                    float uv = au[mi][nj][rg] + bu_;
                    gv = fminf(gv, LIMIT);
                    uv = fminf(fmaxf(uv, -LIMIT), LIMIT);
                    const float glu = gv / (1.f + expf(-ALPHA * gv));
                    const int grow = rbase + r0 + r;
                    const int rr = grow & 255;
                    act[((size_t)(grow >> 8) * 32 + kt) * 8192 + rr * 32 +
                        ((slot ^ ((rr >> 1) & 3)) << 3) + ke] = f2bf((uv + 1.f) * glu);
                }
            }
        }
    }
}

// ---------------------------------------------------------------------------
// GEMM2: 256 entries x 128 out-cols, BK=32. BOTH operands staged contiguous
// from blocked layouts (per-lane sources). Writes raw DOWN linear.
// ---------------------------------------------------------------------------
__global__ __launch_bounds__(512, 4) void k_gemm2(
    const u16* __restrict__ actb, const u16* __restrict__ w2t,
    const int* __restrict__ cnt, const int* __restrict__ rowbase,
    const int* __restrict__ assign, u16* __restrict__ down) {
    const int a = assign[blockIdx.y];
    if (a < 0) return;
    const int e = a >> 16, mt = a & 0xffff;
    const int pan = blockIdx.x;               // 8 panels of 128 out-cols
    const int n0 = pan * 128;
    const int cs = cnt[e], r0 = mt * BM, rbase = rowbase[e];
    __shared__ __align__(16) u16 As[2][BM * BK];    // 2 x 16KB
    __shared__ __align__(16) u16 Bs[2][128 * BK];   // 2 x 8KB
    const int tid = threadIdx.x, lane = tid & 63, wv = tid >> 6;
    // A staging: contiguous 2KB/wave from blocked ACT; PER-LANE src +lane*8
    const u16* ablk = actb + ((size_t)((rbase + r0) >> 8) * 32) * 8192 + wv * 1024 + lane * 8;
    // B staging: contiguous 1KB/wave from blocked W2T; PER-LANE src +lane*8
    const u16* bblk = w2t + ((size_t)(e * 8 + pan) * 32) * 4096 + wv * 512 + lane * 8;
    const int dofsB = wv * 512;
    const int wm = wv >> 1, wn = wv & 1;
    const int lcol = lane & 15, lk = lane >> 4;
    int aoff[4], boff[4];
#pragma unroll
    for (int mi = 0; mi < 4; ++mi) {
        const int r = wm * 64 + mi * 16 + lcol;
        aoff[mi] = r * 64 + ((lk ^ ((r >> 1) & 3)) << 4);
    }
#pragma unroll
    for (int nj = 0; nj < 4; ++nj) {
        const int b = wn * 64 + nj * 16 + lcol;     // 0..127
        boff[nj] = b * 64 + ((lk ^ ((b >> 1) & 3)) << 4);
    }
    f32x4 acc[4][4];
    const f32x4 z = {0.f, 0.f, 0.f, 0.f};
#pragma unroll
    for (int mi = 0; mi < 4; ++mi)
#pragma unroll
        for (int nj = 0; nj < 4; ++nj) acc[mi][nj] = z;
#pragma unroll
    for (int j = 0; j < 2; ++j) gload16(ablk + j * 512, &As[0][wv * 1024 + j * 512]);
    gload16(bblk, &Bs[0][dofsB]);
    pipe_sync();
    int cur = 0;
    for (int t = 0; t < NT; ++t) {
        if (t + 1 < NT) {
            u16* Ad = As[cur ^ 1]; u16* Bd = Bs[cur ^ 1];
#pragma unroll
            for (int j = 0; j < 2; ++j)
                gload16(ablk + (size_t)(t + 1) * 8192 + j * 512, Ad + wv * 1024 + j * 512);
            gload16(bblk + (size_t)(t + 1) * 4096, Bd + dofsB);
        }
        const char* Ab = (const char*)As[cur];
        const char* Bb = (const char*)Bs[cur];
        bf16x8 af[4], bf_[4];
#pragma unroll
        for (int mi = 0; mi < 4; ++mi) af[mi]  = *(const bf16x8*)(Ab + aoff[mi]);
#pragma unroll
        for (int nj = 0; nj < 4; ++nj) bf_[nj] = *(const bf16x8*)(Bb + boff[nj]);
#pragma unroll
        for (int mi = 0; mi < 4; ++mi)
#pragma unroll
            for (int nj = 0; nj < 4; ++nj)
                acc[mi][nj] = __builtin_amdgcn_mfma_f32_16x16x32_bf16(af[mi], bf_[nj], acc[mi][nj], 0, 0, 0);
        pipe_sync();
        cur ^= 1;
    }
#pragma unroll
    for (int mi = 0; mi < 4; ++mi) {
#pragma unroll
        for (int nj = 0; nj < 4; ++nj) {
            const int col = n0 + wn * 64 + nj * 16 + lcol;
#pragma unroll
            for (int rg = 0; rg < 4; ++rg) {
                const int r = wm * 64 + mi * 16 + lk * 4 + rg;
                if (r0 + r < cs)
                    down[(size_t)(rbase + r0 + r) * H_DIM + col] = f2bf(acc[mi][nj][rg]);
            }
        }
    }
}

// ---------------------------------------------------------------------------
// Combine: out[t][h] = w0*(down[row0][h]+b2[e0][h]) + w1*(down[row1][h]+b2[e1][h])
// ---------------------------------------------------------------------------
__global__ __launch_bounds__(256) void k_combine(
    const int* __restrict__ tope, const float2* __restrict__ topw,
    const int2* __restrict__ pos, const int* __restrict__ rowb,
    const float* __restrict__ b2, const u16* __restrict__ down,
    float* __restrict__ out) {
    const int t = blockIdx.x;
    const int c = threadIdx.x * 4;
    const int pk = tope[t];
    const int e0 = pk & 0xff, e1 = pk >> 8;
    const int2 pp = pos[t];
    const float2 w = topw[t];
    const size_t ro0 = (size_t)(rowb[e0] + pp.x) * H_DIM;
    const size_t ro1 = (size_t)(rowb[e1] + pp.y) * H_DIM;
    ushort4 d0 = *(const ushort4*)(down + ro0 + c);
    ushort4 d1 = *(const ushort4*)(down + ro1 + c);
    float4 bb0 = *(const float4*)(b2 + e0 * H_DIM + c);
    float4 bb1 = *(const float4*)(b2 + e1 * H_DIM + c);
    float4 o;
    o.x = w.x * (bf2f(d0.x) + bb0.x) + w.y * (bf2f(d1.x) + bb1.x);
    o.y = w.x * (bf2f(d0.y) + bb0.y) + w.y * (bf2f(d1.y) + bb1.y);
    o.z = w.x * (bf2f(d0.z) + bb0.z) + w.y * (bf2f(d1.z) + bb1.z);
    o.w = w.x * (bf2f(d0.w) + bb0.w) + w.y * (bf2f(d1.w) + bb1.w);
    *(float4*)(out + (size_t)t * H_DIM + c) = o;
}

// ---------------------------------------------------------------------------
extern "C" void kernel_launch(void* const* d_in, const int* in_sizes, int n_in,
                              void* d_out, int out_size, void* d_ws, size_t ws_size,
                              hipStream_t stream) {
    const float* x   = (const float*)d_in[0];
    const float* rw  = (const float*)d_in[1];
    const float* w1  = (const float*)d_in[2];
    const float* b1  = (const float*)d_in[3];
    const float* w2  = (const float*)d_in[4];
    const float* b2  = (const float*)d_in[5];
    float* out = (float*)d_out;
    char* ws = (char*)d_ws;

    if (ws_size < WS_NEED) return;

    u16*    W1T  = (u16*)(ws + WS_W1T);
    u16*    DOWN = (u16*)(ws + WS_DOWN);   // aliases W1T (safe: used after gemm1)
    u16*    W2T  = (u16*)(ws + WS_W2T);
    u16*    ACT  = (u16*)(ws + WS_ACT);
    int*    ETOK = (int*)(ws + WS_ETOK);
    int2*   POS  = (int2*)(ws + WS_POS);
    int*    CNT  = (int*)(ws + WS_CNT);
    int*    ROWB = (int*)(ws + WS_ROWB);
    int*    ASGN = (int*)(ws + WS_ASGN);
    int*    TOPE = (int*)(ws + WS_TOPE);
    float2* TOPW = (float2*)(ws + WS_TOPW);
    u16*    XBF  = (u16*)(ws + WS_XBF);

    hipMemsetAsync(CNT, 0, E_NUM * sizeof(int), stream);

    k_xbf<<<T_TOK * H_DIM / 2048, 256, 0, stream>>>(x, XBF);
    k_transpose_w1<<<dim3(32, 16, 8), 256, 0, stream>>>(w1, W1T);
    k_transpose_w2<<<dim3(16, 16, 8), 256, 0, stream>>>(w2, W2T);
    k_router_top2<<<T_TOK / 4, 256, 0, stream>>>(x, rw, TOPE, TOPW);
    k_router_scatter<<<T_TOK / 256, 256, 0, stream>>>(TOPE, CNT, ETOK, POS);
    k_schedule<<<1, 64, 0, stream>>>(CNT, ROWB, ASGN);
    k_gemm1<<<dim3(16, MAXT), 512, 0, stream>>>(XBF, W1T, b1, ETOK, CNT, ROWB, ASGN, ACT);
    k_gemm2<<<dim3(8, MAXT), 512, 0, stream>>>(ACT, W2T, CNT, ROWB, ASGN, DOWN);
    k_combine<<<T_TOK, 256, 0, stream>>>(TOPE, TOPW, POS, ROWB, b2, DOWN, out);
}